// Round 1
// baseline (945.669 us; speedup 1.0000x reference)
//
#include <hip/hip_runtime.h>
#include <hip/hip_bf16.h>

// GNN message passing: gather(x[src],x[tgt],ef) -> MLP(112->128->128->48, relu,relu,none)
// -> scatter-mean by target -> out = x + update.
// Strategy: bf16 MFMA (16x16x32), persistent blocks, all weights resident in LDS (bf16,
// transposed WT[n][k], K padded to 128), 256-edge activation tile, XOR-swizzled LDS
// (16B granules, g ^= row&15) so A/B frag ds_read_b128 are conflict-free (<=2-way).
// Each wave owns a private 32-edge slab -> no barriers between layers.

#define NN 100000
#define NE 1600000
#define NF 48
#define TOT 112
#define HID 128

typedef __attribute__((ext_vector_type(8))) short short8;   // 8 bf16 (4 VGPRs) MFMA A/B frag
typedef __attribute__((ext_vector_type(4))) float floatx4;  // MFMA C/D frag

__device__ __forceinline__ unsigned short f2bf(float f) {
    union { float f; unsigned u; } v; v.f = f;
    unsigned u = v.u;
    return (unsigned short)((u + 0x7FFFu + ((u >> 16) & 1u)) >> 16);  // RNE
}

// ---- prep: W (fp32, [k][n] row-major) -> WT (bf16, [n][k], k padded to 128 with 0)
__global__ void prep_kernel(const float* __restrict__ W1, const float* __restrict__ W2,
                            const float* __restrict__ W3,
                            unsigned short* __restrict__ wt1, unsigned short* __restrict__ wt2,
                            unsigned short* __restrict__ wt3) {
    int idx = blockIdx.x * 256 + threadIdx.x;  // 38912 total
    if (idx < 16384) {                         // WT1: 128n x 128k
        int n = idx >> 7, k = idx & 127;
        wt1[idx] = (k < TOT) ? f2bf(W1[k * HID + n]) : (unsigned short)0;
    } else if (idx < 32768) {                  // WT2: 128 x 128
        int j = idx - 16384;
        int n = j >> 7, k = j & 127;
        wt2[j] = f2bf(W2[k * HID + n]);
    } else {                                   // WT3: 48n x 128k
        int j = idx - 32768;
        int n = j >> 7, k = j & 127;
        wt3[j] = f2bf(W3[k * NF + n]);
    }
}

// swizzled LDS address helpers: row stride 256 B (128 bf16), granule = 16 B
__device__ __forceinline__ const short8* frag_ptr(const unsigned short* base, int row, int s,
                                                  int lane15, int quad) {
    // A/B frag: lane reads 16B at row (row&15==lane15), k-granule (s*4+quad), swizzled
    return (const short8*)((const char*)base + row * 256 + (((s * 4 + quad) ^ lane15) << 4));
}

__device__ __forceinline__ void layer_128(const unsigned short* __restrict__ lw,
                                          unsigned short* __restrict__ lact,
                                          const float* __restrict__ bias,
                                          int m0, int lane15, int quad) {
    short8 a[2][4];
#pragma unroll
    for (int mt = 0; mt < 2; ++mt)
#pragma unroll
        for (int s = 0; s < 4; ++s)
            a[mt][s] = *frag_ptr(lact, m0 + mt * 16 + lane15, s, lane15, quad);
    floatx4 acc[2][8];
#pragma unroll
    for (int mt = 0; mt < 2; ++mt)
#pragma unroll
        for (int nt = 0; nt < 8; ++nt) acc[mt][nt] = (floatx4){0.f, 0.f, 0.f, 0.f};
#pragma unroll
    for (int nt = 0; nt < 8; ++nt) {
#pragma unroll
        for (int s = 0; s < 4; ++s) {
            short8 b = *frag_ptr(lw, nt * 16 + lane15, s, lane15, quad);
            acc[0][nt] = __builtin_amdgcn_mfma_f32_16x16x32_bf16(a[0][s], b, acc[0][nt], 0, 0, 0);
            acc[1][nt] = __builtin_amdgcn_mfma_f32_16x16x32_bf16(a[1][s], b, acc[1][nt], 0, 0, 0);
        }
    }
    // relu(acc+bias) -> bf16 back into lact (same rows; wave-private slab, no barrier)
#pragma unroll
    for (int mt = 0; mt < 2; ++mt)
#pragma unroll
        for (int nt = 0; nt < 8; ++nt) {
            int n = nt * 16 + lane15;
            float bv = bias[n];
#pragma unroll
            for (int r = 0; r < 4; ++r) {
                int row = m0 + mt * 16 + quad * 4 + r;
                float hv = fmaxf(acc[mt][nt][r] + bv, 0.0f);
                *(unsigned short*)((char*)lact + row * 256 + (((n >> 3) ^ (row & 15)) << 4) +
                                   ((n & 7) << 1)) = f2bf(hv);
            }
        }
}

__launch_bounds__(512, 2)
__global__ void mlp_kernel(const float* __restrict__ x, const int* __restrict__ ei,
                           const float* __restrict__ ef,
                           const unsigned short* __restrict__ wt1,
                           const unsigned short* __restrict__ wt2,
                           const unsigned short* __restrict__ wt3,
                           const float* __restrict__ b1, const float* __restrict__ b2,
                           const float* __restrict__ b3,
                           float* __restrict__ out_acc, float* __restrict__ cnt) {
    __shared__ __align__(16) unsigned short lw1[128 * 128];  // 32 KB
    __shared__ __align__(16) unsigned short lw2[128 * 128];  // 32 KB
    __shared__ __align__(16) unsigned short lw3[48 * 128];   // 12 KB
    __shared__ __align__(16) unsigned short lact[256 * 128]; // 64 KB
    __shared__ float lb[304];

    const int tid = threadIdx.x;
    // ---- stage weights (once per persistent block), swizzled by granule
    const uint4* s1 = (const uint4*)wt1;
    for (int i = tid; i < 2048; i += 512) {
        int n = i >> 4, g = i & 15;
        *(uint4*)((char*)lw1 + n * 256 + ((g ^ (n & 15)) << 4)) = s1[i];
    }
    const uint4* s2 = (const uint4*)wt2;
    for (int i = tid; i < 2048; i += 512) {
        int n = i >> 4, g = i & 15;
        *(uint4*)((char*)lw2 + n * 256 + ((g ^ (n & 15)) << 4)) = s2[i];
    }
    const uint4* s3 = (const uint4*)wt3;
    for (int i = tid; i < 768; i += 512) {
        int n = i >> 4, g = i & 15;
        *(uint4*)((char*)lw3 + n * 256 + ((g ^ (n & 15)) << 4)) = s3[i];
    }
    for (int i = tid; i < 304; i += 512)
        lb[i] = (i < 128) ? b1[i] : (i < 256 ? b2[i - 128] : b3[i - 256]);

    const int lane15 = tid & 15;
    const int quad = (tid & 63) >> 4;
    const int wave = tid >> 6;
    const int m0 = wave * 32;

    for (int tile = blockIdx.x; tile < NE / 256; tile += gridDim.x) {
        const int e0 = tile * 256;
        __syncthreads();  // prev iter's reads done (also covers weight staging, iter 0)
        // ---- gather 256 edges x 112 feats -> bf16 swizzled lact (28 float4 per edge)
        for (int i = tid; i < 256 * 28; i += 512) {
            int el = i / 28;
            int part = i - el * 28;
            int e = e0 + el;
            const float4* p;
            if (part < 12)      p = (const float4*)(x + 48 * (size_t)ei[e]) + part;
            else if (part < 24) p = (const float4*)(x + 48 * (size_t)ei[NE + e]) + (part - 12);
            else                p = (const float4*)(ef + 16 * (size_t)e) + (part - 24);
            float4 v = *p;
            ushort4 h4;
            h4.x = f2bf(v.x); h4.y = f2bf(v.y); h4.z = f2bf(v.z); h4.w = f2bf(v.w);
            int gran = part >> 1;
            *(ushort4*)((char*)lact + el * 256 + ((gran ^ (el & 15)) << 4) +
                        ((part & 1) << 3)) = h4;
            if (part == 12) atomicAdd(cnt + ei[NE + e], 1.0f);
        }
        // zero-pad k=112..127 (granules 14,15)
        for (int i = tid; i < 512; i += 512) {
            int el = i >> 1, g = 14 + (i & 1);
            uint4 z = {0, 0, 0, 0};
            *(uint4*)((char*)lact + el * 256 + ((g ^ (el & 15)) << 4)) = z;
        }
        __syncthreads();
        // ---- layer 1 & 2 (wave-private slab, no barriers between layers)
        layer_128(lw1, lact, lb, m0, lane15, quad);
        layer_128(lw2, lact, lb + 128, m0, lane15, quad);
        // ---- layer 3 (N=48, no relu) + scatter
        short8 a3[2][4];
#pragma unroll
        for (int mt = 0; mt < 2; ++mt)
#pragma unroll
            for (int s = 0; s < 4; ++s)
                a3[mt][s] = *frag_ptr(lact, m0 + mt * 16 + lane15, s, lane15, quad);
        floatx4 acc3[2][3];
#pragma unroll
        for (int mt = 0; mt < 2; ++mt)
#pragma unroll
            for (int nt = 0; nt < 3; ++nt) acc3[mt][nt] = (floatx4){0.f, 0.f, 0.f, 0.f};
#pragma unroll
        for (int nt = 0; nt < 3; ++nt)
#pragma unroll
            for (int s = 0; s < 4; ++s) {
                short8 b = *frag_ptr(lw3, nt * 16 + lane15, s, lane15, quad);
                acc3[0][nt] = __builtin_amdgcn_mfma_f32_16x16x32_bf16(a3[0][s], b, acc3[0][nt], 0, 0, 0);
                acc3[1][nt] = __builtin_amdgcn_mfma_f32_16x16x32_bf16(a3[1][s], b, acc3[1][nt], 0, 0, 0);
            }
#pragma unroll
        for (int mt = 0; mt < 2; ++mt)
#pragma unroll
            for (int r = 0; r < 4; ++r) {
                int e = e0 + m0 + mt * 16 + quad * 4 + r;
                int tg = ei[NE + e];
                float* dst = out_acc + 48 * (size_t)tg;
#pragma unroll
                for (int nt = 0; nt < 3; ++nt) {
                    int n = nt * 16 + lane15;
                    atomicAdd(dst + n, acc3[mt][nt][r] + lb[256 + n]);
                }
            }
    }
}

__global__ void finalize_kernel(const float* __restrict__ x, const float* __restrict__ cnt,
                                float* __restrict__ out) {
    int i = blockIdx.x * 256 + threadIdx.x;  // exactly NN*48
    out[i] = x[i] + out[i] / fmaxf(cnt[i / 48], 1.0f);
}

extern "C" void kernel_launch(void* const* d_in, const int* in_sizes, int n_in,
                              void* d_out, int out_size, void* d_ws, size_t ws_size,
                              hipStream_t stream) {
    const float* x  = (const float*)d_in[0];
    const int*   ei = (const int*)d_in[1];   // (2, NE): [0..NE)=src, [NE..2NE)=tgt
    const float* ef = (const float*)d_in[2];
    const float* W1 = (const float*)d_in[3];
    const float* b1 = (const float*)d_in[4];
    const float* W2 = (const float*)d_in[5];
    const float* b2 = (const float*)d_in[6];
    const float* W3 = (const float*)d_in[7];
    const float* b3 = (const float*)d_in[8];
    float* out = (float*)d_out;

    char* ws = (char*)d_ws;
    float* cnt = (float*)ws;                               // NN*4 = 400000 B
    unsigned short* wt1 = (unsigned short*)(ws + 409600);  // 32 KB
    unsigned short* wt2 = wt1 + 16384;                     // 32 KB
    unsigned short* wt3 = wt2 + 16384;                     // 12 KB

    hipMemsetAsync(out, 0, (size_t)out_size * sizeof(float), stream);
    hipMemsetAsync(cnt, 0, (size_t)NN * sizeof(float), stream);
    prep_kernel<<<152, 256, 0, stream>>>(W1, W2, W3, wt1, wt2, wt3);
    mlp_kernel<<<256, 512, 0, stream>>>(x, ei, ef, wt1, wt2, wt3, b1, b2, b3, out, cnt);
    finalize_kernel<<<NN * NF / 256, 256, 0, stream>>>(x, cnt, out);
}

// Round 2
// 851.614 us; speedup vs baseline: 1.1104x; 1.1104x over previous
//
#include <hip/hip_runtime.h>
#include <hip/hip_bf16.h>

// GNN message passing: gather(x[src],x[tgt],ef) -> MLP(112->128->128->48) -> scatter-mean.
// R2: counting-sort edges by target (hist/alloc/place), MLP walks target-sorted order,
// per-tile LDS segment-reduce -> ~17 segments/tile -> 15x fewer global atomics.
// block=1024 (16 waves/CU, 50% occupancy at 1 block/CU LDS), wave-private 16-edge slab.
// fp32 message tile aliases act LDS at 256B/row so msg writes stay inside own slab rows.

#define NN 100000
#define NE 1600000
#define NF 48
#define TOT 112
#define HID 128
#define NTILE 6250  // NE/256

typedef __attribute__((ext_vector_type(8))) short short8;
typedef __attribute__((ext_vector_type(4))) float floatx4;

__device__ __forceinline__ unsigned short f2bf(float f) {
    union { float f; unsigned u; } v; v.f = f;
    unsigned u = v.u;
    return (unsigned short)((u + 0x7FFFu + ((u >> 16) & 1u)) >> 16);  // RNE
}

// ---- prep: W fp32 [k][n] -> WT bf16 [n][k], k padded to 128
__global__ void prep_kernel(const float* __restrict__ W1, const float* __restrict__ W2,
                            const float* __restrict__ W3,
                            unsigned short* __restrict__ wt1, unsigned short* __restrict__ wt2,
                            unsigned short* __restrict__ wt3) {
    int idx = blockIdx.x * 256 + threadIdx.x;
    if (idx < 16384) {
        int n = idx >> 7, k = idx & 127;
        wt1[idx] = (k < TOT) ? f2bf(W1[k * HID + n]) : (unsigned short)0;
    } else if (idx < 32768) {
        int j = idx - 16384; int n = j >> 7, k = j & 127;
        wt2[j] = f2bf(W2[k * HID + n]);
    } else if (idx < 38912) {
        int j = idx - 32768; int n = j >> 7, k = j & 127;
        wt3[j] = f2bf(W3[k * NF + n]);
    }
}

__global__ void hist_kernel(const int* __restrict__ ei, int* __restrict__ cnt) {
    int e = blockIdx.x * 256 + threadIdx.x;  // NE exact
    atomicAdd(cnt + ei[NE + e], 1);
}

__global__ void alloc_kernel(const int* __restrict__ cnt, int* __restrict__ off,
                             int* __restrict__ counter) {
    int n = blockIdx.x * 256 + threadIdx.x;
    if (n < NN) off[n] = atomicAdd(counter, cnt[n]);  // order irrelevant: ranges disjoint
}

__global__ void place_kernel(const int* __restrict__ ei, const int* __restrict__ off,
                             int* __restrict__ rank, int* __restrict__ eid_s,
                             int* __restrict__ src_s, int* __restrict__ tgt_s) {
    int e = blockIdx.x * 256 + threadIdx.x;  // NE exact
    int t = ei[NE + e];
    int r = atomicAdd(rank + t, 1);
    int p = off[t] + r;
    eid_s[p] = e; src_s[p] = ei[e]; tgt_s[p] = t;
}

// swizzled LDS frag helper: row stride 256B, 16B granules, g ^= row&15
__device__ __forceinline__ const short8* frag_ptr(const unsigned short* base, int row, int s,
                                                  int lane15, int quad) {
    return (const short8*)((const char*)base + row * 256 + (((s * 4 + quad) ^ lane15) << 4));
}

__device__ __forceinline__ void layer16(const unsigned short* __restrict__ lw,
                                        unsigned short* __restrict__ lact,
                                        const float* __restrict__ bias,
                                        int m0, int l15, int q) {
    short8 a[4];
#pragma unroll
    for (int s = 0; s < 4; ++s) a[s] = *frag_ptr(lact, m0 + l15, s, l15, q);
    floatx4 acc[8];
#pragma unroll
    for (int nt = 0; nt < 8; ++nt) acc[nt] = (floatx4){0.f, 0.f, 0.f, 0.f};
#pragma unroll
    for (int nt = 0; nt < 8; ++nt)
#pragma unroll
        for (int s = 0; s < 4; ++s) {
            short8 b = *frag_ptr(lw, nt * 16 + l15, s, l15, q);
            acc[nt] = __builtin_amdgcn_mfma_f32_16x16x32_bf16(a[s], b, acc[nt], 0, 0, 0);
        }
#pragma unroll
    for (int nt = 0; nt < 8; ++nt) {
        int n = nt * 16 + l15;
        float bv = bias[n];
#pragma unroll
        for (int r = 0; r < 4; ++r) {
            int row = m0 + q * 4 + r;
            float hv = fmaxf(acc[nt][r] + bv, 0.0f);
            *(unsigned short*)((char*)lact + row * 256 + (((n >> 3) ^ (row & 15)) << 4) +
                               ((n & 7) << 1)) = f2bf(hv);
        }
    }
}

__launch_bounds__(1024, 4)
__global__ void mlp_kernel(const float* __restrict__ x, const float* __restrict__ ef,
                           const int* __restrict__ eid_s, const int* __restrict__ src_s,
                           const int* __restrict__ tgt_s,
                           const unsigned short* __restrict__ wt1,
                           const unsigned short* __restrict__ wt2,
                           const unsigned short* __restrict__ wt3,
                           const float* __restrict__ b1, const float* __restrict__ b2,
                           float* __restrict__ out_acc) {
    __shared__ __align__(16) unsigned short lw1[128 * 128];
    __shared__ __align__(16) unsigned short lw2[128 * 128];
    __shared__ __align__(16) unsigned short lw3[48 * 128];
    __shared__ __align__(16) unsigned short lact[256 * 128];  // 64KB; msg fp32 aliases (64 f/row)
    __shared__ float lb[256];
    __shared__ int ltgt[256];
    __shared__ int seg_start[257];
    __shared__ int seg_tgt[256];
    __shared__ int nseg;

    const int tid = threadIdx.x;
    float* lmsg = (float*)lact;  // row stride 64 floats (256B) -> stays in own slab rows

    const uint4* s1 = (const uint4*)wt1;
    for (int i = tid; i < 2048; i += 1024) {
        int n = i >> 4, g = i & 15;
        *(uint4*)((char*)lw1 + n * 256 + ((g ^ (n & 15)) << 4)) = s1[i];
    }
    const uint4* s2 = (const uint4*)wt2;
    for (int i = tid; i < 2048; i += 1024) {
        int n = i >> 4, g = i & 15;
        *(uint4*)((char*)lw2 + n * 256 + ((g ^ (n & 15)) << 4)) = s2[i];
    }
    const uint4* s3 = (const uint4*)wt3;
    if (tid < 768) {
        int n = tid >> 4, g = tid & 15;
        *(uint4*)((char*)lw3 + n * 256 + ((g ^ (n & 15)) << 4)) = s3[tid];
    }
    if (tid < 256) lb[tid] = (tid < 128) ? b1[tid] : b2[tid - 128];

    const int l15 = tid & 15;
    const int q = (tid & 63) >> 4;
    const int ln = tid & 63;
    const int wave = tid >> 6;
    const int m0 = wave * 16;

    for (int tile = blockIdx.x; tile < NTILE; tile += gridDim.x) {
        const int p0 = tile * 256;
        __syncthreads();  // prev tile's reduce done (covers staging on iter 0)
        // ---- gather 256 sorted edges -> bf16 swizzled lact
        for (int i = tid; i < 256 * 28; i += 1024) {
            int el = i / 28;
            int part = i - el * 28;
            int sp = p0 + el;
            const float4* gp;
            if (part < 12)      gp = (const float4*)(x + 48 * (size_t)src_s[sp]) + part;
            else if (part < 24) gp = (const float4*)(x + 48 * (size_t)tgt_s[sp]) + (part - 12);
            else                gp = (const float4*)(ef + 16 * (size_t)eid_s[sp]) + (part - 24);
            float4 v = *gp;
            ushort4 h4;
            h4.x = f2bf(v.x); h4.y = f2bf(v.y); h4.z = f2bf(v.z); h4.w = f2bf(v.w);
            int gran = part >> 1;
            *(ushort4*)((char*)lact + el * 256 + ((gran ^ (el & 15)) << 4) +
                        ((part & 1) << 3)) = h4;
        }
        if (tid < 512) {  // zero-pad k=112..127
            int el = tid >> 1, g = 14 + (tid & 1);
            uint4 z = {0, 0, 0, 0};
            *(uint4*)((char*)lact + el * 256 + ((g ^ (el & 15)) << 4)) = z;
        }
        if (tid < 256) ltgt[tid] = tgt_s[p0 + tid];
        __syncthreads();
        // ---- 3 layers, wave-private 16-row slab
        layer16(lw1, lact, lb, m0, l15, q);
        layer16(lw2, lact, lb + 128, m0, l15, q);
        short8 a3[4];
#pragma unroll
        for (int s = 0; s < 4; ++s) a3[s] = *frag_ptr(lact, m0 + l15, s, l15, q);
        floatx4 acc3[3];
#pragma unroll
        for (int nt = 0; nt < 3; ++nt) acc3[nt] = (floatx4){0.f, 0.f, 0.f, 0.f};
#pragma unroll
        for (int nt = 0; nt < 3; ++nt)
#pragma unroll
            for (int s = 0; s < 4; ++s) {
                short8 b = *frag_ptr(lw3, nt * 16 + l15, s, l15, q);
                acc3[nt] = __builtin_amdgcn_mfma_f32_16x16x32_bf16(a3[s], b, acc3[nt], 0, 0, 0);
            }
        // fp32 msg into own slab rows (bias b3 deferred to finalize)
#pragma unroll
        for (int nt = 0; nt < 3; ++nt) {
            int col = nt * 16 + l15;
#pragma unroll
            for (int r = 0; r < 4; ++r) lmsg[(m0 + q * 4 + r) * 64 + col] = acc3[nt][r];
        }
        // ---- wave 0: enumerate target runs in this tile
        if (wave == 0) {
            int base = 0;
#pragma unroll
            for (int c = 0; c < 4; ++c) {
                int p = c * 64 + ln;
                int t = ltgt[p];
                int flag = (p == 0) || (t != ltgt[p - 1]);
                unsigned long long mask = __ballot(flag);
                int sid = base + __popcll(mask & ((1ull << ln) - 1ull));
                if (flag) { seg_start[sid] = p; seg_tgt[sid] = t; }
                base += __popcll(mask);
            }
            if (ln == 0) { nseg = base; }
            seg_start[(ln == 0) ? base : 256] = 256;  // sentinel (lane0 writes real one)
        }
        __syncthreads();
        // ---- segment reduce + one atomic per (segment, feature)
        if (ln < 48) {
            for (int s = wave; s < nseg; s += 16) {
                int a = seg_start[s], bnd = seg_start[s + 1];
                float s0 = 0.f, s1 = 0.f, s2 = 0.f, s3 = 0.f;
                const float* mcol = lmsg + ln;
                int p = a;
                for (; p + 3 < bnd; p += 4) {
                    s0 += mcol[p * 64]; s1 += mcol[(p + 1) * 64];
                    s2 += mcol[(p + 2) * 64]; s3 += mcol[(p + 3) * 64];
                }
                for (; p < bnd; ++p) s0 += mcol[p * 64];
                float sum = (s0 + s1) + (s2 + s3);
                atomicAdd(out_acc + 48 * (size_t)seg_tgt[s] + ln, sum);
            }
        }
    }
}

__global__ void finalize_kernel(const float* __restrict__ x, const int* __restrict__ cnt,
                                const float* __restrict__ b3, float* __restrict__ out) {
    int i = blockIdx.x * 256 + threadIdx.x;  // NN*48 exact
    float c = (float)cnt[i / 48];
    float upd = (c > 0.f) ? (out[i] / c + b3[i % 48]) : 0.f;
    out[i] = x[i] + upd;
}

extern "C" void kernel_launch(void* const* d_in, const int* in_sizes, int n_in,
                              void* d_out, int out_size, void* d_ws, size_t ws_size,
                              hipStream_t stream) {
    const float* x  = (const float*)d_in[0];
    const int*   ei = (const int*)d_in[1];
    const float* ef = (const float*)d_in[2];
    const float* W1 = (const float*)d_in[3];
    const float* b1 = (const float*)d_in[4];
    const float* W2 = (const float*)d_in[5];
    const float* b2 = (const float*)d_in[6];
    const float* W3 = (const float*)d_in[7];
    const float* b3 = (const float*)d_in[8];
    float* out = (float*)d_out;

    char* ws = (char*)d_ws;
    int* cnt     = (int*)ws;                    // 400000 B (pad 409600)
    int* rankc   = (int*)(ws + 409600);
    int* off     = (int*)(ws + 819200);
    int* counter = (int*)(ws + 1228800);        // 256 B
    unsigned short* wt1 = (unsigned short*)(ws + 1229056);
    unsigned short* wt2 = wt1 + 16384;
    unsigned short* wt3 = wt2 + 16384;
    int* eid_s = (int*)(ws + 1310720);
    int* src_s = eid_s + NE;
    int* tgt_s = src_s + NE;                    // total ~20.5 MB

    hipMemsetAsync(out, 0, (size_t)out_size * sizeof(float), stream);
    hipMemsetAsync(cnt, 0, (size_t)NN * sizeof(int), stream);
    hipMemsetAsync(rankc, 0, (size_t)NN * sizeof(int), stream);
    hipMemsetAsync(counter, 0, sizeof(int), stream);
    prep_kernel<<<152, 256, 0, stream>>>(W1, W2, W3, wt1, wt2, wt3);
    hist_kernel<<<NTILE, 256, 0, stream>>>(ei, cnt);
    alloc_kernel<<<391, 256, 0, stream>>>(cnt, off, counter);
    place_kernel<<<NTILE, 256, 0, stream>>>(ei, off, rankc, eid_s, src_s, tgt_s);
    mlp_kernel<<<256, 1024, 0, stream>>>(x, ef, eid_s, src_s, tgt_s, wt1, wt2, wt3,
                                         b1, b2, out);
    finalize_kernel<<<NN * NF / 256, 256, 0, stream>>>(x, cnt, b3, out);
}